// Round 1
// baseline (2695.239 us; speedup 1.0000x reference)
//
#include <hip/hip_runtime.h>
#include <hip/hip_bf16.h>
#include <math.h>

// Shapes (fixed for this problem instance)
// B=2 N=4 G=2 Ck=64 Cv=512 H=W=64 HW=4096 L=256 TOPL=64 Cin=1152 BN=8 BNG=16

typedef __attribute__((ext_vector_type(8))) short bf16x8;
typedef __attribute__((ext_vector_type(4))) float f32x4;

static __device__ __forceinline__ short f2b(float f){
  __hip_bfloat16 h = __float2bfloat16(f);
  short s; __builtin_memcpy(&s, &h, 2); return s;
}

static __device__ __forceinline__ float wred_max(float v){
  #pragma unroll
  for (int off = 32; off > 0; off >>= 1) v = fmaxf(v, __shfl_xor(v, off));
  return v;
}
static __device__ __forceinline__ float wred_sum(float v){
  #pragma unroll
  for (int off = 32; off > 0; off >>= 1) v += __shfl_xor(v, off);
  return v;
}

#define FMA16(X0,X1,X2,X3,KV) \
  acc[0]+=X0.x*KV; acc[1]+=X0.y*KV; acc[2]+=X0.z*KV; acc[3]+=X0.w*KV; \
  acc[4]+=X1.x*KV; acc[5]+=X1.y*KV; acc[6]+=X1.z*KV; acc[7]+=X1.w*KV; \
  acc[8]+=X2.x*KV; acc[9]+=X2.y*KV; acc[10]+=X2.z*KV; acc[11]+=X2.w*KV; \
  acc[12]+=X3.x*KV; acc[13]+=X3.y*KV; acc[14]+=X3.z*KV; acc[15]+=X3.w*KV;

// ---------------- prep kernels ----------------

// xT[b][hw][k] = qk[b][k][hw]; xTn = l2norm over k
__global__ void k_prep_x(const float* __restrict__ qk, float* __restrict__ xT, float* __restrict__ xTn){
  int idx = blockIdx.x*256 + threadIdx.x;   // 8192 = B*HW
  int b = idx >> 12, hw = idx & 4095;
  float v[64]; float ss = 0.f;
  #pragma unroll
  for (int k=0;k<64;k++){ v[k] = qk[((size_t)b*64 + k)*4096 + hw]; ss += v[k]*v[k]; }
  float inv = 1.f/(sqrtf(ss) + 1e-6f);
  #pragma unroll
  for (int k=0;k<64;k++){ xT[(size_t)idx*64 + k] = v[k]; xTn[(size_t)idx*64 + k] = v[k]*inv; }
}

// weights0 = masks copy; kn0 = l2norm(kappa0) over k
__global__ void k_init_w_kn(const float* __restrict__ masks, const float* __restrict__ kappa0,
                            float* __restrict__ wts, float* __restrict__ kn){
  int t = blockIdx.x*256 + threadIdx.x;   // 65536
  if (t < 16*4096) wts[t] = masks[t];
  if (t < 16*256){
    int bng = t >> 8, l = t & 255;
    float ss = 0.f;
    #pragma unroll 4
    for (int k=0;k<64;k++){ float v = kappa0[((size_t)bng*64 + k)*256 + l]; ss += v*v; }
    float inv = 1.f/(sqrtf(ss) + 1e-6f);
    #pragma unroll 4
    for (int k=0;k<64;k++) kn[((size_t)bng*64 + k)*256 + l] = kappa0[((size_t)bng*64 + k)*256 + l]*inv;
  }
}

// Wt[cv][r*1152+c] = W[cv][c][r]  (bf16)
__global__ void k_prep_wt(const float* __restrict__ Wsrc, short* __restrict__ Wt){
  int t = blockIdx.x*256 + threadIdx.x;   // 512*10368
  int cv = t / 10368;
  int rc = t - cv*10368;
  int r = rc / 1152;
  int c = rc - r*1152;
  Wt[t] = f2b(Wsrc[((size_t)cv*1152 + c)*9 + r]);
}

// fin channels [512,1024) = qv (broadcast over n), bf16
__global__ void k_qv_fin(const float* __restrict__ qv, short* __restrict__ finb){
  int t = blockIdx.x*256 + threadIdx.x;   // 8*512*4096 = 2^24
  int bn = t >> 21;
  int rem = t & ((1<<21)-1);
  int b = bn >> 2;
  finb[(size_t)bn*1152*4096 + (size_t)512*4096 + rem] = f2b(qv[(size_t)b*512*4096 + rem]);
}

// ---------------- EM loop kernels ----------------

// zz[bng][hw][l] = softmax_l(x·kn / tau) * w    block: 256 thr, 16 pixels
__global__ __launch_bounds__(256) void k_zz(const float* __restrict__ xT, const float* __restrict__ kn,
                                            const float* __restrict__ wts, float* __restrict__ zzb){
  int blk = blockIdx.x;                 // 4096 = 16 bng * 256 tiles
  int bng = blk >> 8;
  int hw0 = (blk & 255) * 16;
  int b = bng >> 3;
  int t = threadIdx.x;
  int lane = t & 63, wid = t >> 6;
  __shared__ float xs[64][16];
  __shared__ float redm[4], reds[4];
  {
    int k = t & 63, pq = t >> 6;
    #pragma unroll
    for (int p = pq; p < 16; p += 4)
      xs[k][p] = xT[((size_t)b*4096 + hw0 + p)*64 + k];
  }
  float acc[16];
  #pragma unroll
  for (int p=0;p<16;p++) acc[p] = 0.f;
  __syncthreads();
  const float* knp = kn + (size_t)bng*16384 + t;
  #pragma unroll 2
  for (int k=0;k<64;k++){
    float knv = knp[k*256];
    float4 x0 = *(const float4*)&xs[k][0];
    float4 x1 = *(const float4*)&xs[k][4];
    float4 x2 = *(const float4*)&xs[k][8];
    float4 x3 = *(const float4*)&xs[k][12];
    FMA16(x0,x1,x2,x3,knv)
  }
  #pragma unroll
  for (int p=0;p<16;p++){
    float v = acc[p];
    float m = wred_max(v);
    if (lane==0) redm[wid] = m;
    __syncthreads();
    m = fmaxf(fmaxf(redm[0],redm[1]), fmaxf(redm[2],redm[3]));
    float e = __expf((v - m) * 20.0f);
    float s = wred_sum(e);
    if (lane==0) reds[wid] = s;
    __syncthreads();
    s = reds[0]+reds[1]+reds[2]+reds[3];
    float wgt = wts[bng*4096 + hw0 + p];
    zzb[((size_t)bng*4096 + hw0 + p)*256 + t] = e/s*wgt;
  }
}

// partial kappa-numerator and zita sums over 256-hw chunks
__global__ __launch_bounds__(1024) void k_part(const float* __restrict__ qk, const float* __restrict__ zzb,
                                               float* __restrict__ kpart, float* __restrict__ zpart){
  int bng = blockIdx.x >> 4, ch = blockIdx.x & 15;   // 256 blocks
  int b = bng >> 3;
  int t = threadIdx.x; int l = t & 255; int kq = t >> 8;
  __shared__ float xs[64][80];
  float acc[16];
  #pragma unroll
  for (int j=0;j<16;j++) acc[j]=0.f;
  float zs = 0.f;
  for (int sc=0; sc<4; sc++){
    int hwb = ch*256 + sc*64;
    __syncthreads();
    {
      int hw_l = t & 63, kk = t >> 6;
      #pragma unroll
      for (int k = kk; k < 64; k += 16)
        xs[hw_l][k] = qk[((size_t)b*64 + k)*4096 + hwb + hw_l];
    }
    __syncthreads();
    #pragma unroll 2
    for (int hw_l=0; hw_l<64; hw_l++){
      float zv = zzb[((size_t)bng*4096 + hwb + hw_l)*256 + l];
      zs += zv;
      const float* xp = &xs[hw_l][kq*16];
      float4 x0 = *(const float4*)(xp);
      float4 x1 = *(const float4*)(xp+4);
      float4 x2 = *(const float4*)(xp+8);
      float4 x3 = *(const float4*)(xp+12);
      FMA16(x0,x1,x2,x3,zv)
    }
  }
  #pragma unroll
  for (int j=0;j<16;j++)
    kpart[(((size_t)bng*16 + ch)*64 + kq*16 + j)*256 + l] = acc[j];
  if (kq == 0) zpart[((size_t)bng*16 + ch)*256 + l] = zs;
}

// finalize zita, kappa, kn = l2norm(kappa)
__global__ __launch_bounds__(1024) void k_fin(const float* __restrict__ kpart, const float* __restrict__ zpart,
                                              const float* __restrict__ kappa0, const float* __restrict__ zita0,
                                              float* __restrict__ kn, float* __restrict__ zita){
  int bng = blockIdx.x; int t = threadIdx.x; int l = t & 255; int kq = t >> 8;
  float z0 = zita0[bng*256 + l];
  float zs = z0;
  #pragma unroll
  for (int ch=0; ch<16; ch++) zs += zpart[((size_t)bng*16 + ch)*256 + l];
  if (kq==0) zita[bng*256 + l] = zs;
  float inv = 1.f/zs;
  float kap[16]; float ss = 0.f;
  #pragma unroll
  for (int j=0;j<16;j++){
    int k = kq*16 + j;
    float a = z0 * kappa0[((size_t)bng*64 + k)*256 + l];
    #pragma unroll
    for (int ch=0; ch<16; ch++) a += kpart[(((size_t)bng*16 + ch)*64 + k)*256 + l];
    float kv = a*inv; kap[j] = kv; ss += kv*kv;
  }
  __shared__ float ssr[4][256];
  ssr[kq][l] = ss;
  __syncthreads();
  float tot = ssr[0][l]+ssr[1][l]+ssr[2][l]+ssr[3][l];
  float ninv = 1.f/(sqrtf(tot) + 1e-6f);
  #pragma unroll
  for (int j=0;j<16;j++) kn[((size_t)bng*64 + kq*16 + j)*256 + l] = kap[j]*ninv;
}

// sww: weights = m * (1 - props)   block: 512 thr (g0 = waves0-3, g1 = waves4-7), 16 pixels
__global__ __launch_bounds__(512) void k_sww(const float* __restrict__ xTn, const float* __restrict__ kn,
                                             const float* __restrict__ masks, float* __restrict__ wts){
  int blk = blockIdx.x;                 // 2048 = 8 bn * 256 tiles
  int bnI = blk >> 8;
  int hw0 = (blk & 255)*16;
  int b = bnI >> 2;
  int t = threadIdx.x;
  int lane = t & 63, wid = t >> 6;
  int g = t >> 8; int l = t & 255;
  int bng = bnI*2 + g;
  __shared__ float xs[64][16];
  __shared__ float redm[8], reds[8];
  {
    int k = t & 63, pq = t >> 6;
    #pragma unroll
    for (int p = pq; p < 16; p += 8)
      xs[k][p] = xTn[((size_t)b*4096 + hw0 + p)*64 + k];
  }
  float knr[64];
  const float* knp = kn + (size_t)bng*16384 + l;
  #pragma unroll
  for (int k=0;k<64;k++) knr[k] = knp[k*256];
  float acc[16];
  #pragma unroll
  for (int p=0;p<16;p++) acc[p]=0.f;
  __syncthreads();
  #pragma unroll 2
  for (int k=0;k<64;k++){
    float knv = knr[k];
    float4 x0 = *(const float4*)&xs[k][0];
    float4 x1 = *(const float4*)&xs[k][4];
    float4 x2 = *(const float4*)&xs[k][8];
    float4 x3 = *(const float4*)&xs[k][12];
    FMA16(x0,x1,x2,x3,knv)
  }
  #pragma unroll
  for (int p=0;p<16;p++){
    float v = acc[p];
    float m = wred_max(v);
    if (lane==0) redm[wid] = m;
    __syncthreads();
    m = fmaxf(fmaxf(fmaxf(redm[0],redm[1]),fmaxf(redm[2],redm[3])),
              fmaxf(fmaxf(redm[4],redm[5]),fmaxf(redm[6],redm[7])));
    float e = __expf((v - m) * 20.0f);
    float s = wred_sum(e);
    if (lane==0) reds[wid] = s;
    __syncthreads();
    float s0 = reds[0]+reds[1]+reds[2]+reds[3];
    float s1 = reds[4]+reds[5]+reds[6]+reds[7];
    if (lane==0 && (wid==0 || wid==4)){
      float sg = g ? s1 : s0;
      wts[bng*4096 + hw0 + p] = masks[bng*4096 + hw0 + p]*(1.f - sg/(s0+s1));
    }
  }
}

// affinity softmax -> p_aff[bn][hw][gl] fp32 (coalesced row writes)
__global__ __launch_bounds__(512) void k_aff(const float* __restrict__ xTn, const float* __restrict__ kn,
                                             float* __restrict__ paff){
  int blk = blockIdx.x;                 // 2048
  int bnI = blk >> 8;
  int hw0 = (blk & 255)*16;
  int b = bnI >> 2;
  int t = threadIdx.x;
  int lane = t & 63, wid = t >> 6;
  int g = t >> 8; int l = t & 255;
  int bng = bnI*2 + g;
  __shared__ float xs[64][16];
  __shared__ float redm[8], reds[8];
  {
    int k = t & 63, pq = t >> 6;
    #pragma unroll
    for (int p = pq; p < 16; p += 8)
      xs[k][p] = xTn[((size_t)b*4096 + hw0 + p)*64 + k];
  }
  float knr[64];
  const float* knp = kn + (size_t)bng*16384 + l;
  #pragma unroll
  for (int k=0;k<64;k++) knr[k] = knp[k*256];
  float acc[16];
  #pragma unroll
  for (int p=0;p<16;p++) acc[p]=0.f;
  __syncthreads();
  #pragma unroll 2
  for (int k=0;k<64;k++){
    float knv = knr[k];
    float4 x0 = *(const float4*)&xs[k][0];
    float4 x1 = *(const float4*)&xs[k][4];
    float4 x2 = *(const float4*)&xs[k][8];
    float4 x3 = *(const float4*)&xs[k][12];
    FMA16(x0,x1,x2,x3,knv)
  }
  #pragma unroll
  for (int p=0;p<16;p++){
    float v = acc[p];
    float m = wred_max(v);
    if (lane==0) redm[wid] = m;
    __syncthreads();
    m = fmaxf(fmaxf(fmaxf(redm[0],redm[1]),fmaxf(redm[2],redm[3])),
              fmaxf(fmaxf(redm[4],redm[5]),fmaxf(redm[6],redm[7])));
    float e = __expf((v - m) * 20.0f);
    float s = wred_sum(e);
    if (lane==0) reds[wid] = s;
    __syncthreads();
    float tot = reds[0]+reds[1]+reds[2]+reds[3]+reds[4]+reds[5]+reds[6]+reds[7];
    paff[((size_t)bnI*4096 + hw0 + p)*512 + t] = e/tot;
  }
}

// ---------------- top-k / S channels ----------------

static __device__ __forceinline__ float topk_cum(float va, float vb, float vc, float vd, int lane){
  float run = 0.f, cme = 0.f;
  #pragma unroll 2
  for (int tt=0; tt<64; tt++){
    float m = fmaxf(fmaxf(va,vb), fmaxf(vc,vd));
    float wm = wred_max(m);
    run += wm;
    if (lane == tt) cme = run;
    unsigned long long ball = __ballot(m == wm);
    int wl = __ffsll(ball) - 1;
    if (lane == wl){
      if (va == wm) va = -1.f;
      else if (vb == wm) vb = -1.f;
      else if (vc == wm) vc = -1.f;
      else vd = -1.f;
    }
  }
  return cme;
}

__global__ __launch_bounds__(256) void k_topk(const float* __restrict__ paff, short* __restrict__ finb){
  int wid = threadIdx.x >> 6, lane = threadIdx.x & 63;
  int px = blockIdx.x*4 + wid;           // 32768 pixels
  int bn = px >> 12, hw = px & 4095;
  const float* row = paff + (size_t)px*512;
  float4 a0 = *(const float4*)(row + lane*4);
  float4 a1 = *(const float4*)(row + 256 + lane*4);
  float c0 = topk_cum(a0.x,a0.y,a0.z,a0.w, lane);
  float c1 = topk_cum(a1.x,a1.y,a1.z,a1.w, lane);
  float sf = c0/(c0+c1);
  size_t base = (size_t)bn*1152*4096;
  finb[base + (size_t)(1024+lane)*4096 + hw] = f2b(sf);
  finb[base + (size_t)(1088+lane)*4096 + hw] = f2b(1.f - sf);
}

// ---------------- MFMA GEMMs ----------------

// nu: C[cv][l] = qv_mem[bn] (Cv x HW) . zz[bng] (HW x L); epilogue -> mv2 bf16
__global__ __launch_bounds__(256) void k_nu(const float* __restrict__ qvm, const float* __restrict__ zzb,
                                            const float* __restrict__ nu0, const float* __restrict__ zita0,
                                            const float* __restrict__ zita, short* __restrict__ mv2){
  constexpr int AP = 40;
  __shared__ short lA[64*AP];
  __shared__ short lB[64*AP];
  int blk = blockIdx.x;                  // 512 = 16 bng * 8 cvb * 4 lb
  int bng = blk >> 5, cvb = (blk >> 2) & 7, lb = blk & 3;
  int bn = bng >> 1, g = bng & 1;
  int t = threadIdx.x, lane = t & 63, w = t >> 6;
  int wm = w >> 1, wn = w & 1;
  int quad = lane >> 4, fr = lane & 15;
  f32x4 acc[2][2] = {};
  const float* Ab = qvm + ((size_t)bn*512 + cvb*64)*4096;
  const float* Bb = zzb + (size_t)bng*4096*256 + lb*64;
  int arow = t >> 2, acg = (t & 3)*8;
  int bhw = t & 31, blg = (t >> 5)*8;
  for (int k0 = 0; k0 < 4096; k0 += 32){
    __syncthreads();
    {
      const float* s = Ab + (size_t)arow*4096 + k0 + acg;
      float4 f0 = *(const float4*)s, f1 = *(const float4*)(s+4);
      bf16x8 v;
      v[0]=f2b(f0.x); v[1]=f2b(f0.y); v[2]=f2b(f0.z); v[3]=f2b(f0.w);
      v[4]=f2b(f1.x); v[5]=f2b(f1.y); v[6]=f2b(f1.z); v[7]=f2b(f1.w);
      *(bf16x8*)&lA[arow*AP + acg] = v;
    }
    {
      const float* s = Bb + (size_t)(k0 + bhw)*256 + blg;
      float4 f0 = *(const float4*)s, f1 = *(const float4*)(s+4);
      lB[(blg+0)*AP + bhw] = f2b(f0.x);
      lB[(blg+1)*AP + bhw] = f2b(f0.y);
      lB[(blg+2)*AP + bhw] = f2b(f0.z);
      lB[(blg+3)*AP + bhw] = f2b(f0.w);
      lB[(blg+4)*AP + bhw] = f2b(f1.x);
      lB[(blg+5)*AP + bhw] = f2b(f1.y);
      lB[(blg+6)*AP + bhw] = f2b(f1.z);
      lB[(blg+7)*AP + bhw] = f2b(f1.w);
    }
    __syncthreads();
    int koff = quad*8;
    bf16x8 a0 = *(const bf16x8*)&lA[(wm*32 +  0 + fr)*AP + koff];
    bf16x8 a1 = *(const bf16x8*)&lA[(wm*32 + 16 + fr)*AP + koff];
    bf16x8 b0 = *(const bf16x8*)&lB[(wn*32 +  0 + fr)*AP + koff];
    bf16x8 b1 = *(const bf16x8*)&lB[(wn*32 + 16 + fr)*AP + koff];
    acc[0][0] = __builtin_amdgcn_mfma_f32_16x16x32_bf16(a0,b0,acc[0][0],0,0,0);
    acc[0][1] = __builtin_amdgcn_mfma_f32_16x16x32_bf16(a0,b1,acc[0][1],0,0,0);
    acc[1][0] = __builtin_amdgcn_mfma_f32_16x16x32_bf16(a1,b0,acc[1][0],0,0,0);
    acc[1][1] = __builtin_amdgcn_mfma_f32_16x16x32_bf16(a1,b1,acc[1][1],0,0,0);
  }
  #pragma unroll
  for (int mf=0; mf<2; mf++)
  #pragma unroll
  for (int nf=0; nf<2; nf++)
  #pragma unroll
  for (int r=0;r<4;r++){
    int cv = cvb*64 + wm*32 + mf*16 + quad*4 + r;
    int l  = lb*64 + wn*32 + nf*16 + fr;
    float c = acc[mf][nf][r];
    float z0 = zita0[bng*256 + l];
    float nv = (z0 * nu0[((size_t)bng*512 + cv)*256 + l] + c) / zita[bng*256 + l];
    mv2[((size_t)bn*512 + cv)*512 + g*256 + l] = f2b(nv);
  }
}

// mem_out: C[cv][hw] = mv2[bn] (Cv x 2L) . p_aff[bn] (2L x HW) -> fin channels [0,512) bf16
__global__ __launch_bounds__(256) void k_mem(const short* __restrict__ mv2, const float* __restrict__ paff,
                                             short* __restrict__ finb){
  constexpr int BP = 40;
  __shared__ short lB[256*BP];
  int blk = blockIdx.x;                  // 1024 = 8 bn * 8 cvb * 16 hwb
  int bn = blk >> 7, cvb = (blk >> 4) & 7, hwb = blk & 15;
  int t = threadIdx.x, lane = t & 63, w = t >> 6;
  int quad = lane >> 4, fr = lane & 15;
  f32x4 acc[4][4] = {};
  const short* Ab = mv2 + ((size_t)bn*512 + cvb*64)*512;
  const float* Bb = paff + ((size_t)bn*4096 + hwb*256)*512;
  for (int k0=0; k0<512; k0+=32){
    __syncthreads();
    {
      const float* s = Bb + (size_t)t*512 + k0;
      #pragma unroll
      for (int q=0;q<4;q++){
        float4 f0 = *(const float4*)(s + q*8);
        float4 f1 = *(const float4*)(s + q*8 + 4);
        bf16x8 v;
        v[0]=f2b(f0.x); v[1]=f2b(f0.y); v[2]=f2b(f0.z); v[3]=f2b(f0.w);
        v[4]=f2b(f1.x); v[5]=f2b(f1.y); v[6]=f2b(f1.z); v[7]=f2b(f1.w);
        *(bf16x8*)&lB[t*BP + q*8] = v;
      }
    }
    __syncthreads();
    int koff = quad*8;
    bf16x8 af[4];
    #pragma unroll
    for (int mf=0; mf<4; mf++)
      af[mf] = *(const bf16x8*)(Ab + (size_t)(mf*16 + fr)*512 + k0 + koff);
    #pragma unroll
    for (int nf=0; nf<4; nf++){
      bf16x8 bv = *(const bf16x8*)&lB[(w*64 + nf*16 + fr)*BP + koff];
      #pragma unroll
      for (int mf=0; mf<4; mf++)
        acc[mf][nf] = __builtin_amdgcn_mfma_f32_16x16x32_bf16(af[mf], bv, acc[mf][nf],0,0,0);
    }
  }
  #pragma unroll
  for (int mf=0;mf<4;mf++)
  #pragma unroll
  for (int nf=0;nf<4;nf++)
  #pragma unroll
  for (int r=0;r<4;r++){
    int cv = cvb*64 + mf*16 + quad*4 + r;
    int hw = hwb*256 + w*64 + nf*16 + fr;
    finb[(size_t)bn*1152*4096 + (size_t)cv*4096 + hw] = f2b(acc[mf][nf][r]);
  }
}

// fused conv (f & a) + gating. implicit GEMM: C[cv][x] over K = 1152c x 9r
// block: 64 cv x 4 y-rows (wave per row, 64 x each)
__global__ __launch_bounds__(256, 2) void k_conv(const short* __restrict__ finb, const short* __restrict__ Wtf,
                                                 const short* __restrict__ Wta, const float* __restrict__ bfv,
                                                 const float* __restrict__ bav, float* __restrict__ out){
  constexpr int CP = 40;
  __shared__ short lF[6*66*CP];          // [row 0..5][px 0..65][c]
  __shared__ short lWf[2][64*CP];
  __shared__ short lWa[2][64*CP];
  int blk = blockIdx.x;                  // 1024 = 8 bn * 8 cvb * 16 yb
  int bn = blk >> 7, cvb = (blk >> 4) & 7, yb = blk & 15;
  int t = threadIdx.x, lane = t & 63, w = t >> 6;
  int quad = lane >> 4, fr = lane & 15;
  f32x4 accF[4][4] = {}, accA[4][4] = {};
  const short* fB = finb + (size_t)bn*1152*4096;
  const short* WfB = Wtf + (size_t)(cvb*64)*10368;
  const short* WaB = Wta + (size_t)(cvb*64)*10368;
  int y0 = yb*4;
  if (t < 192){
    int row = t/32, side = (t>>4)&1, c2 = t&15;
    *(unsigned int*)&lF[(row*66 + (side?65:0))*CP + c2*2] = 0u;
  }
  int sx = t & 63, scq = t >> 6;
  int wcv = t >> 2, wcg = (t & 3)*8;
  for (int cb = 0; cb < 36; cb++){
    int c0 = cb*32;
    for (int c2 = scq; c2 < 16; c2 += 4){
      int c = c2*2;
      const short* base = fB + (size_t)(c0 + c)*4096 + sx;
      #pragma unroll
      for (int row = 0; row < 6; row++){
        int gy = y0 - 1 + row;
        unsigned int v = 0u;
        if (gy >= 0 && gy < 64){
          unsigned int lo = (unsigned short)base[gy*64];
          unsigned int hi = (unsigned short)base[4096 + gy*64];
          v = lo | (hi << 16);
        }
        *(unsigned int*)&lF[(row*66 + sx + 1)*CP + c] = v;
      }
    }
    {
      *(bf16x8*)&lWf[0][wcv*CP + wcg] = *(const bf16x8*)(WfB + (size_t)wcv*10368 + c0 + wcg);
      *(bf16x8*)&lWa[0][wcv*CP + wcg] = *(const bf16x8*)(WaB + (size_t)wcv*10368 + c0 + wcg);
    }
    __syncthreads();
    #pragma unroll
    for (int r = 0; r < 9; r++){
      if (r < 8){
        *(bf16x8*)&lWf[(r+1)&1][wcv*CP + wcg] = *(const bf16x8*)(WfB + (size_t)wcv*10368 + (r+1)*1152 + c0 + wcg);
        *(bf16x8*)&lWa[(r+1)&1][wcv*CP + wcg] = *(const bf16x8*)(WaB + (size_t)wcv*10368 + (r+1)*1152 + c0 + wcg);
      }
      int dy = r/3, dx = r - dy*3;
      int koff = quad*8;
      bf16x8 af[4], aa[4];
      #pragma unroll
      for (int mf=0; mf<4; mf++){
        af[mf] = *(const bf16x8*)&lWf[r&1][(mf*16 + fr)*CP + koff];
        aa[mf] = *(const bf16x8*)&lWa[r&1][(mf*16 + fr)*CP + koff];
      }
      #pragma unroll
      for (int nf=0; nf<4; nf++){
        bf16x8 bv = *(const bf16x8*)&lF[((w+dy)*66 + nf*16 + fr + dx)*CP + koff];
        #pragma unroll
        for (int mf=0; mf<4; mf++){
          accF[mf][nf] = __builtin_amdgcn_mfma_f32_16x16x32_bf16(af[mf], bv, accF[mf][nf],0,0,0);
          accA[mf][nf] = __builtin_amdgcn_mfma_f32_16x16x32_bf16(aa[mf], bv, accA[mf][nf],0,0,0);
        }
      }
      __syncthreads();
    }
  }
  #pragma unroll
  for (int mf=0;mf<4;mf++)
  #pragma unroll
  for (int nf=0;nf<4;nf++)
  #pragma unroll
  for (int r4=0;r4<4;r4++){
    int cv = cvb*64 + mf*16 + quad*4 + r4;
    int x = nf*16 + fr;
    float fv = accF[mf][nf][r4] + bfv[cv];
    float av = accA[mf][nf][r4] + bav[cv];
    out[(size_t)bn*512*4096 + (size_t)cv*4096 + (size_t)(y0 + w)*64 + x] = fv/(1.f + __expf(-av));
  }
}

// ---------------- launch ----------------

extern "C" void kernel_launch(void* const* d_in, const int* in_sizes, int n_in,
                              void* d_out, int out_size, void* d_ws, size_t ws_size,
                              hipStream_t stream){
  const float* qk     = (const float*)d_in[0];
  const float* qv     = (const float*)d_in[1];
  const float* qvm    = (const float*)d_in[2];
  const float* masks  = (const float*)d_in[3];
  const float* kappa0 = (const float*)d_in[4];
  const float* nu0    = (const float*)d_in[5];
  const float* zita0  = (const float*)d_in[6];
  const float* Wf     = (const float*)d_in[7];
  const float* bfb    = (const float*)d_in[8];
  const float* Wa     = (const float*)d_in[9];
  const float* bab    = (const float*)d_in[10];
  float* out = (float*)d_out;

  float* ws    = (float*)d_ws;
  float* zzb   = ws;                      // 16,777,216 f  (reused as p_aff later)
  float* kpart = zzb + 16777216;          // 4,194,304 f
  float* zpart = kpart + 4194304;         // 65,536 f
  float* kn    = zpart + 65536;           // 262,144 f
  float* zita  = kn + 262144;             // 4,096 f
  float* wts   = zita + 4096;             // 65,536 f
  float* xT    = wts + 65536;             // 524,288 f
  float* xTn   = xT + 524288;             // 524,288 f
  short* mv2   = (short*)(xTn + 524288);  // 4,194,304 s
  short* finb  = mv2 + 4194304;           // 37,748,736 s
  short* Wtf   = finb + 37748736;         // 5,308,416 s
  short* Wta   = Wtf + 5308416;           // 5,308,416 s  (total ~195 MB)

  k_prep_x<<<32, 256, 0, stream>>>(qk, xT, xTn);
  k_init_w_kn<<<256, 256, 0, stream>>>(masks, kappa0, wts, kn);
  k_prep_wt<<<20736, 256, 0, stream>>>(Wf, Wtf);
  k_prep_wt<<<20736, 256, 0, stream>>>(Wa, Wta);
  k_qv_fin<<<65536, 256, 0, stream>>>(qv, finb);

  for (int it = 0; it < 4; ++it){
    k_zz<<<4096, 256, 0, stream>>>(xT, kn, wts, zzb);
    k_part<<<256, 1024, 0, stream>>>(qk, zzb, kpart, zpart);
    k_fin<<<16, 1024, 0, stream>>>(kpart, zpart, kappa0, zita0, kn, zita);
    if (it < 3) k_sww<<<2048, 512, 0, stream>>>(xTn, kn, masks, wts);
  }

  k_nu<<<512, 256, 0, stream>>>(qvm, zzb, nu0, zita0, zita, mv2);
  k_aff<<<2048, 512, 0, stream>>>(xTn, kn, zzb /* becomes p_aff */);
  k_topk<<<8192, 256, 0, stream>>>(zzb, finb);
  k_mem<<<1024, 256, 0, stream>>>(mv2, zzb, finb);
  k_conv<<<1024, 256, 0, stream>>>(finb, Wtf, Wta, bfb, bab, out);
}